// Round 1
// baseline (855.903 us; speedup 1.0000x reference)
//
#include <hip/hip_runtime.h>
#include <math.h>

// Problem constants (N,E,H,W,C) = (4, 64, 512, 512, 64)
#define NIT 4
#define ED  64
#define CL  64
#define PX  262144   // 512*512

// workspace layout (floats)
#define W_CNT 0        // N*C counts
#define W_SUM 256      // N*C*E sums -> means (in place)
#define W_MSQ 16640    // N*C |mean|^2
#define W_INT 16896    // N*C sum(pmap * mask)
#define W_DEN 17152    // N*C sum(pmap^2)
#define W_VAR 17408    // N   var-term raw sum
#define W_DR  17412    // N   beta*dist + gamma*reg
#define W_TOT 17416

__device__ __forceinline__ void atomAddG(float* p, float v){
  __hip_atomic_fetch_add(p, v, __ATOMIC_RELAXED, __HIP_MEMORY_SCOPE_AGENT);
}
__device__ __forceinline__ void atomAddL(float* p, float v){
  __hip_atomic_fetch_add(p, v, __ATOMIC_RELAXED, __HIP_MEMORY_SCOPE_WORKGROUP);
}

// ---------------- kernel A: per-cluster sums & counts (segment sum) ----------
// grid = 4 items * 128 blocks, 2048 px/block, 8 px/thread (2 x float4 groups)
__global__ __launch_bounds__(256) void k_sums(const float* __restrict__ emb,
                                              const int* __restrict__ tgt,
                                              float* __restrict__ ws){
  __shared__ float s_sum[CL*65];   // +1 pad: bank = (t+e)%32, spread across banks
  __shared__ float s_cnt[CL];
  const int tid = threadIdx.x;
  for (int i = tid; i < CL*65; i += 256) s_sum[i] = 0.f;
  if (tid < CL) s_cnt[tid] = 0.f;
  __syncthreads();
  const int n   = blockIdx.x >> 7;
  const int blk = blockIdx.x & 127;
  const float* eb = emb + (size_t)n * ED * PX;
  const int*   tg = tgt + (size_t)n * PX;
  const int base = blk * 2048;
  const int4 t0 = *(const int4*)(tg + base + tid*4);
  const int4 t1 = *(const int4*)(tg + base + 1024 + tid*4);
  atomAddL(&s_cnt[t0.x], 1.f); atomAddL(&s_cnt[t0.y], 1.f);
  atomAddL(&s_cnt[t0.z], 1.f); atomAddL(&s_cnt[t0.w], 1.f);
  atomAddL(&s_cnt[t1.x], 1.f); atomAddL(&s_cnt[t1.y], 1.f);
  atomAddL(&s_cnt[t1.z], 1.f); atomAddL(&s_cnt[t1.w], 1.f);
  const int a0 = t0.x*65, a1 = t0.y*65, a2 = t0.z*65, a3 = t0.w*65;
  const int b0 = t1.x*65, b1 = t1.y*65, b2 = t1.z*65, b3 = t1.w*65;
  #pragma unroll 4
  for (int e = 0; e < ED; ++e){
    const float* row = eb + (size_t)e * PX + base;
    const float4 v0 = *(const float4*)(row + tid*4);
    const float4 v1 = *(const float4*)(row + 1024 + tid*4);
    atomAddL(&s_sum[a0+e], v0.x); atomAddL(&s_sum[a1+e], v0.y);
    atomAddL(&s_sum[a2+e], v0.z); atomAddL(&s_sum[a3+e], v0.w);
    atomAddL(&s_sum[b0+e], v1.x); atomAddL(&s_sum[b1+e], v1.y);
    atomAddL(&s_sum[b2+e], v1.z); atomAddL(&s_sum[b3+e], v1.w);
  }
  __syncthreads();
  float* wsum = ws + W_SUM + n*CL*ED;
  for (int i = tid; i < CL*ED; i += 256)
    atomAddG(&wsum[i], s_sum[(i>>6)*65 + (i&63)]);
  if (tid < CL) atomAddG(&ws[W_CNT + n*CL + tid], s_cnt[tid]);
}

// ---------------- kernel B: finalize means; msq; dist+reg terms --------------
__global__ __launch_bounds__(256) void k_fin(float* __restrict__ ws){
  __shared__ float sm[CL][ED+1];
  __shared__ float red[256];
  const int tid = threadIdx.x;
  const int n = blockIdx.x;
  float* wsum = ws + W_SUM + n*CL*ED;
  const float* wcnt = ws + W_CNT + n*CL;
  for (int i = tid; i < CL*ED; i += 256){
    const int c = i >> 6, e = i & 63;
    const float m = wsum[i] / fmaxf(wcnt[c], 1.f);
    sm[c][e] = m;
    wsum[i] = m;   // means in place
  }
  __syncthreads();
  float reg_local = 0.f;
  if (tid < CL){
    float s = 0.f;
    #pragma unroll
    for (int e = 0; e < ED; ++e) s += sm[tid][e]*sm[tid][e];
    ws[W_MSQ + n*CL + tid] = s;
    reg_local = sqrtf(s + 1e-12f);
  }
  float pair_local = 0.f;
  for (int idx = tid; idx < CL*CL; idx += 256){
    const int i = idx >> 6, j = idx & 63;
    if (i != j){
      float s = 0.f;
      #pragma unroll
      for (int e = 0; e < ED; ++e){ const float d = sm[i][e]-sm[j][e]; s += d*d; }
      const float h = fmaxf(4.0f - sqrtf(s + 1e-12f), 0.f);  // 2*delta_dist = 4
      pair_local += h*h;
    }
  }
  red[tid] = pair_local; __syncthreads();
  for (int s = 128; s > 0; s >>= 1){ if (tid < s) red[tid] += red[tid+s]; __syncthreads(); }
  const float pair_sum = red[0];
  __syncthreads();
  red[tid] = reg_local; __syncthreads();
  for (int s = 128; s > 0; s >>= 1){ if (tid < s) red[tid] += red[tid+s]; __syncthreads(); }
  if (tid == 0)
    ws[W_DR + n] = pair_sum / 4032.0f + 0.001f * red[0] / 64.0f;  // beta=1, gamma=1e-3
}

// ---------------- kernel C: main per-pixel pass ------------------------------
// grid = 4 items * 256 blocks, 1024 px/block, 2 iters x 2 px/thread
__global__ __launch_bounds__(256) void k_main(const float* __restrict__ emb,
                                              const int* __restrict__ tgt,
                                              float* __restrict__ ws){
  __shared__ float s_m[CL*ED];     // broadcast reads -> no padding needed
  __shared__ float s_msq[CL];
  __shared__ float s_icnt[CL];
  __shared__ float s_den[CL];
  __shared__ float s_int[CL];
  __shared__ float s_var[4];
  const int tid = threadIdx.x;
  const int n   = blockIdx.x >> 8;
  const int blk = blockIdx.x & 255;
  const float* wm = ws + W_SUM + n*CL*ED;
  for (int i = tid; i < CL*ED; i += 256) s_m[i] = wm[i];
  if (tid < CL){
    s_msq[tid] = ws[W_MSQ + n*CL + tid];
    s_icnt[tid] = 1.f / fmaxf(ws[W_CNT + n*CL + tid], 1.f);
    s_den[tid] = 0.f;
    s_int[tid] = 0.f;
  }
  __syncthreads();
  const float* eb = emb + (size_t)n * ED * PX;
  const int*   tg = tgt + (size_t)n * PX;
  const int lane = tid & 63;
  const float kExpScale = -0.42144206f;   // ln(0.9)/delta_var^2
  float var_local = 0.f;
  float den_mine = 0.f;                   // accumulates den for cluster == lane
  for (int it = 0; it < 2; ++it){
    const int p0 = blk*1024 + it*512 + tid;
    const int p1 = p0 + 256;
    const int ta = tg[p0], tb = tg[p1];
    float ev0[ED], ev1[ED];
    float e2a = 0.f, e2b = 0.f;
    #pragma unroll
    for (int e = 0; e < ED; ++e){
      const float va = eb[(size_t)e*PX + p0];
      const float vb = eb[(size_t)e*PX + p1];
      ev0[e] = va; ev1[e] = vb;
      e2a += va*va; e2b += vb*vb;
    }
    float pmta = 0.f, pmtb = 0.f, d2ta = 0.f, d2tb = 0.f;
    #pragma unroll 2
    for (int c = 0; c < CL; ++c){
      const float4* mrow = (const float4*)&s_m[c*ED];
      float a0=0.f,a1=0.f,a2=0.f,a3=0.f, b0=0.f,b1=0.f,b2=0.f,b3=0.f;
      #pragma unroll
      for (int e4 = 0; e4 < ED/4; ++e4){
        const float4 m = mrow[e4];
        a0 += m.x*ev0[e4*4+0]; a1 += m.y*ev0[e4*4+1];
        a2 += m.z*ev0[e4*4+2]; a3 += m.w*ev0[e4*4+3];
        b0 += m.x*ev1[e4*4+0]; b1 += m.y*ev1[e4*4+1];
        b2 += m.z*ev1[e4*4+2]; b3 += m.w*ev1[e4*4+3];
      }
      const float dota = (a0+a1)+(a2+a3);
      const float dotb = (b0+b1)+(b2+b3);
      const float msq = s_msq[c];
      const float d2a = fmaxf(e2a + msq - 2.f*dota, 0.f);
      const float d2b = fmaxf(e2b + msq - 2.f*dotb, 0.f);
      const float pma = __expf(d2a * kExpScale);
      const float pmb = __expf(d2b * kExpScale);
      float r = pma*pma + pmb*pmb;
      #pragma unroll
      for (int m_ = 1; m_ < 64; m_ <<= 1) r += __shfl_xor(r, m_, 64);
      den_mine += (lane == c) ? r : 0.f;   // lane l owns cluster l for this wave
      const bool oa = (c == ta), ob = (c == tb);
      pmta = oa ? pma : pmta; d2ta = oa ? d2a : d2ta;
      pmtb = ob ? pmb : pmtb; d2tb = ob ? d2b : d2tb;
    }
    atomAddL(&s_int[ta], pmta);
    atomAddL(&s_int[tb], pmtb);
    const float da = sqrtf(d2ta + 1e-12f), db = sqrtf(d2tb + 1e-12f);
    const float ha = fmaxf(da - 0.5f, 0.f), hb = fmaxf(db - 0.5f, 0.f);
    var_local += ha*ha*s_icnt[ta] + hb*hb*s_icnt[tb];
  }
  atomAddL(&s_den[lane], den_mine);
  #pragma unroll
  for (int m_ = 1; m_ < 64; m_ <<= 1) var_local += __shfl_xor(var_local, m_, 64);
  if (lane == 0) s_var[tid >> 6] = var_local;
  __syncthreads();
  if (tid < CL){
    atomAddG(&ws[W_DEN + n*CL + tid], s_den[tid]);
    atomAddG(&ws[W_INT + n*CL + tid], s_int[tid]);
  }
  if (tid == 0)
    atomAddG(&ws[W_VAR + n], s_var[0]+s_var[1]+s_var[2]+s_var[3]);
}

// ---------------- kernel D: final combine ------------------------------------
__global__ __launch_bounds__(256) void k_out(const float* __restrict__ ws,
                                             float* __restrict__ out){
  __shared__ float dsum[NIT];
  __shared__ float tot;
  const int tid = threadIdx.x;
  if (tid < NIT) dsum[tid] = 0.f;
  if (tid == 0) tot = 0.f;
  __syncthreads();
  const int n = tid >> 6, c = tid & 63;
  const float cnt   = ws[W_CNT + n*CL + c];
  const float inter = ws[W_INT + n*CL + c];
  const float den   = ws[W_DEN + n*CL + c] + cnt;
  const float dice  = 2.f * inter / fmaxf(den, 1e-6f);
  atomAddL(&dsum[n], dice);
  __syncthreads();
  if (tid < NIT){
    const float loss = ws[W_VAR + tid] / 64.0f   // alpha * var_sum / C
                     + ws[W_DR + tid]            // beta*dist + gamma*reg
                     + (1.f - dsum[tid] / 64.0f);// instance term
    atomAddL(&tot, loss);
  }
  __syncthreads();
  if (tid == 0) out[0] = tot * 0.25f;            // mean over N=4 items
}

extern "C" void kernel_launch(void* const* d_in, const int* in_sizes, int n_in,
                              void* d_out, int out_size, void* d_ws, size_t ws_size,
                              hipStream_t stream){
  (void)in_sizes; (void)n_in; (void)out_size; (void)ws_size;
  const float* emb = (const float*)d_in[0];
  const int*   tgt = (const int*)d_in[1];
  float* ws  = (float*)d_ws;
  float* out = (float*)d_out;
  hipMemsetAsync(d_ws, 0, W_TOT*sizeof(float), stream);
  k_sums<<<NIT*128, 256, 0, stream>>>(emb, tgt, ws);
  k_fin <<<NIT,     256, 0, stream>>>(ws);
  k_main<<<NIT*256, 256, 0, stream>>>(emb, tgt, ws);
  k_out <<<1,       256, 0, stream>>>(ws, out);
}

// Round 3
// 700.955 us; speedup vs baseline: 1.2211x; 1.2211x over previous
//
#include <hip/hip_runtime.h>
#include <math.h>

// Problem constants (N,E,H,W,C) = (4, 64, 512, 512, 64)
#define NIT 4
#define ED  64
#define CL  64
#define PX  262144   // 512*512

// workspace layout (floats)
#define W_CNT 0        // N*C counts
#define W_SUM 256      // N*C*E sums -> means (in place)
#define W_MSQ 16640    // N*C |mean|^2
#define W_INT 16896    // N*C sum(pmap * mask)
#define W_DEN 17152    // N*C sum(pmap^2)
#define W_VAR 17408    // N   var-term raw sum
#define W_DR  17412    // N   beta*dist + gamma*reg
#define W_TOT 17416

#define CHUNKS 8       // chunks per wave
#define CPX 32         // pixels per chunk
#define RSTRIDE 68     // floats per pixel row in LDS (272B, 16B-aligned rows)

__device__ __forceinline__ void atomAddG(float* p, float v){
  __hip_atomic_fetch_add(p, v, __ATOMIC_RELAXED, __HIP_MEMORY_SCOPE_AGENT);
}
__device__ __forceinline__ float readlanef(float v, int l){
  return __uint_as_float(__builtin_amdgcn_readlane(__float_as_uint(v), l));
}

// ---------------- kernel A: per-cluster sums & counts (one-hot dense, no atomics)
// grid = 4 items * 256 blocks, 4 waves/block, each wave: 8 chunks x 32 px.
// lane l owns cluster l: sum_r[e] += v[e][p] * (t_p == l)  (predicated FMA)
__global__ __launch_bounds__(256) void k_sums(const float* __restrict__ emb,
                                              const int* __restrict__ tgt,
                                              float* __restrict__ ws){
  __shared__ float s_px[4][CPX*RSTRIDE];   // 34.8 KB
  __shared__ float s_cnt[CL];
  const int tid  = threadIdx.x;
  const int lane = tid & 63;
  const int w    = tid >> 6;
  const int n    = blockIdx.x >> 8;
  const int blk  = blockIdx.x & 255;
  const float* eb = emb + (size_t)n * ED * PX;
  const int*   tg = tgt + (size_t)n * PX;
  const int px4 = lane & 7;    // pixel-quad this lane loads
  const int eh  = lane >> 3;   // e-slice this lane loads
  float* srow = s_px[w];
  float sum_r[ED];
  #pragma unroll
  for (int e = 0; e < ED; ++e) sum_r[e] = 0.f;
  float cnt_r = 0.f;
  const int wave_id = blk*4 + w;

  for (int ch = 0; ch < CHUNKS; ++ch){
    const int base = wave_id*(CHUNKS*CPX) + ch*CPX;
    const int t_r = tg[base + (lane & 31)];
    // stage 32 px (transposed: LDS row = pixel, 64 floats)
    #pragma unroll
    for (int e0 = 0; e0 < ED; e0 += 8){
      const float4 v4 = *(const float4*)(eb + (size_t)(e0+eh)*PX + base + px4*4);
      const int wb = px4*(4*RSTRIDE) + e0 + eh;
      srow[wb]             = v4.x;
      srow[wb +   RSTRIDE] = v4.y;
      srow[wb + 2*RSTRIDE] = v4.z;
      srow[wb + 3*RSTRIDE] = v4.w;
    }
    // same-wave DS ordering: no barrier needed (private region per wave)
    for (int j = 0; j < CPX; ++j){
      const int tj = __builtin_amdgcn_readlane(t_r, j);
      const float pf = (lane == tj) ? 1.f : 0.f;   // one-hot
      cnt_r += pf;
      const float4* row = (const float4*)(srow + j*RSTRIDE);
      #pragma unroll
      for (int k = 0; k < 16; ++k){
        const float4 v = row[k];              // broadcast read, conflict-free
        sum_r[4*k+0] = fmaf(v.x, pf, sum_r[4*k+0]);
        sum_r[4*k+1] = fmaf(v.y, pf, sum_r[4*k+1]);
        sum_r[4*k+2] = fmaf(v.z, pf, sum_r[4*k+2]);
        sum_r[4*k+3] = fmaf(v.w, pf, sum_r[4*k+3]);
      }
    }
  }
  // ---- block merge: barrier-phased non-atomic LDS adds, then coalesced global atomics
  float* s_acc = &s_px[0][0];   // reuse as [64][65]
  __syncthreads();
  for (int w2 = 0; w2 < 4; ++w2){
    if (w == w2){
      if (w2 == 0){
        #pragma unroll
        for (int e = 0; e < ED; ++e) s_acc[lane*65+e] = sum_r[e];
        if (w == 0) s_cnt[lane] = cnt_r;
      } else {
        #pragma unroll
        for (int e = 0; e < ED; ++e) s_acc[lane*65+e] += sum_r[e];
        s_cnt[lane] += cnt_r;
      }
    }
    __syncthreads();
  }
  float* wsum = ws + W_SUM + n*CL*ED;
  #pragma unroll
  for (int i = 0; i < 16; ++i){
    const int idx = i*256 + tid;
    atomAddG(&wsum[idx], s_acc[(idx>>6)*65 + (idx&63)]);
  }
  if (tid < CL) atomAddG(&ws[W_CNT + n*CL + tid], s_cnt[tid]);
}

// ---------------- kernel B: finalize means; msq; dist+reg terms --------------
__global__ __launch_bounds__(256) void k_fin(float* __restrict__ ws){
  __shared__ float sm[CL][ED+1];
  __shared__ float red[256];
  const int tid = threadIdx.x;
  const int n = blockIdx.x;
  float* wsum = ws + W_SUM + n*CL*ED;
  const float* wcnt = ws + W_CNT + n*CL;
  for (int i = tid; i < CL*ED; i += 256){
    const int c = i >> 6, e = i & 63;
    const float m = wsum[i] / fmaxf(wcnt[c], 1.f);
    sm[c][e] = m;
    wsum[i] = m;   // means in place
  }
  __syncthreads();
  float reg_local = 0.f;
  if (tid < CL){
    float s = 0.f;
    #pragma unroll
    for (int e = 0; e < ED; ++e) s += sm[tid][e]*sm[tid][e];
    ws[W_MSQ + n*CL + tid] = s;
    reg_local = sqrtf(s + 1e-12f);
  }
  float pair_local = 0.f;
  for (int idx = tid; idx < CL*CL; idx += 256){
    const int i = idx >> 6, j = idx & 63;
    if (i != j){
      float s = 0.f;
      #pragma unroll
      for (int e = 0; e < ED; ++e){ const float d = sm[i][e]-sm[j][e]; s += d*d; }
      const float h = fmaxf(4.0f - sqrtf(s + 1e-12f), 0.f);  // 2*delta_dist = 4
      pair_local += h*h;
    }
  }
  red[tid] = pair_local; __syncthreads();
  for (int s = 128; s > 0; s >>= 1){ if (tid < s) red[tid] += red[tid+s]; __syncthreads(); }
  const float pair_sum = red[0];
  __syncthreads();
  red[tid] = reg_local; __syncthreads();
  for (int s = 128; s > 0; s >>= 1){ if (tid < s) red[tid] += red[tid+s]; __syncthreads(); }
  if (tid == 0)
    ws[W_DR + n] = pair_sum / 4032.0f + 0.001f * red[0] / 64.0f;
}

// ---------------- kernel C: main per-pixel pass (lane owns cluster) ----------
// Per pixel: wave broadcasts pixel row from LDS; lane c computes dot with its
// mean (64 VGPRs), d2, pmap. den/int/var accumulate in per-lane registers.
__global__ __launch_bounds__(256) void k_main(const float* __restrict__ emb,
                                              const int* __restrict__ tgt,
                                              float* __restrict__ ws){
  __shared__ float s_px[4][CPX*RSTRIDE];
  const int tid  = threadIdx.x;
  const int lane = tid & 63;
  const int w    = tid >> 6;
  const int n    = blockIdx.x >> 8;
  const int blk  = blockIdx.x & 255;
  const float* eb = emb + (size_t)n * ED * PX;
  const int*   tg = tgt + (size_t)n * PX;
  const float* wm = ws + W_SUM + n*CL*ED;
  float mean_r[ED];
  #pragma unroll
  for (int k = 0; k < 16; ++k){
    const float4 m4 = *(const float4*)(wm + lane*ED + 4*k);
    mean_r[4*k+0]=m4.x; mean_r[4*k+1]=m4.y; mean_r[4*k+2]=m4.z; mean_r[4*k+3]=m4.w;
  }
  const float msq  = ws[W_MSQ + n*CL + lane];
  const float icnt = 1.f / fmaxf(ws[W_CNT + n*CL + lane], 1.f);
  const int px4 = lane & 7;
  const int eh  = lane >> 3;
  float* srow = s_px[w];
  float den_acc = 0.f, int_acc = 0.f, var_acc = 0.f;
  const int wave_id = blk*4 + w;

  for (int ch = 0; ch < CHUNKS; ++ch){
    const int base = wave_id*(CHUNKS*CPX) + ch*CPX;
    const int t_r = tg[base + (lane & 31)];
    float e2p[4] = {0.f,0.f,0.f,0.f};
    #pragma unroll
    for (int e0 = 0; e0 < ED; e0 += 8){
      const float4 v4 = *(const float4*)(eb + (size_t)(e0+eh)*PX + base + px4*4);
      e2p[0] = fmaf(v4.x, v4.x, e2p[0]);
      e2p[1] = fmaf(v4.y, v4.y, e2p[1]);
      e2p[2] = fmaf(v4.z, v4.z, e2p[2]);
      e2p[3] = fmaf(v4.w, v4.w, e2p[3]);
      const int wb = px4*(4*RSTRIDE) + e0 + eh;
      srow[wb]             = v4.x;
      srow[wb +   RSTRIDE] = v4.y;
      srow[wb + 2*RSTRIDE] = v4.z;
      srow[wb + 3*RSTRIDE] = v4.w;
    }
    // combine e2 partials across the 8 e-slice lane groups (xor 8,16,32)
    #pragma unroll
    for (int m = 8; m < 64; m <<= 1){
      e2p[0] += __shfl_xor(e2p[0], m, 64);
      e2p[1] += __shfl_xor(e2p[1], m, 64);
      e2p[2] += __shfl_xor(e2p[2], m, 64);
      e2p[3] += __shfl_xor(e2p[3], m, 64);
    }
    for (int j4 = 0; j4 < CPX/4; ++j4){
      #pragma unroll
      for (int kk = 0; kk < 4; ++kk){
        const int j = j4*4 + kk;
        const float e2j = readlanef(e2p[kk], j4);
        const int   tj  = __builtin_amdgcn_readlane(t_r, j);
        float d0=0.f, d1=0.f, d2s=0.f, d3=0.f;
        const float4* row = (const float4*)(srow + j*RSTRIDE);
        #pragma unroll
        for (int k = 0; k < 16; ++k){
          const float4 v = row[k];            // broadcast read
          d0  = fmaf(mean_r[4*k+0], v.x, d0);
          d1  = fmaf(mean_r[4*k+1], v.y, d1);
          d2s = fmaf(mean_r[4*k+2], v.z, d2s);
          d3  = fmaf(mean_r[4*k+3], v.w, d3);
        }
        const float dot = (d0+d1)+(d2s+d3);
        const float dd  = fmaxf(e2j + msq - 2.f*dot, 0.f);
        const float pm  = __expf(dd * -0.42144207f);  // ln(0.9)/0.25
        den_acc = fmaf(pm, pm, den_acc);
        const bool own = (lane == tj);
        int_acc += own ? pm : 0.f;
        const float dist = sqrtf(dd + 1e-12f);
        const float h = fmaxf(dist - 0.5f, 0.f);
        var_acc += own ? h*h*icnt : 0.f;
      }
    }
  }
  atomAddG(&ws[W_DEN + n*CL + lane], den_acc);
  atomAddG(&ws[W_INT + n*CL + lane], int_acc);
  #pragma unroll
  for (int m = 1; m < 64; m <<= 1) var_acc += __shfl_xor(var_acc, m, 64);
  if (lane == 0) atomAddG(&ws[W_VAR + n], var_acc);
  (void)tid;
}

// ---------------- kernel D: final combine ------------------------------------
__global__ __launch_bounds__(256) void k_out(const float* __restrict__ ws,
                                             float* __restrict__ out){
  __shared__ float dsum[NIT];
  __shared__ float tot;
  const int tid = threadIdx.x;
  if (tid < NIT) dsum[tid] = 0.f;
  if (tid == 0) tot = 0.f;
  __syncthreads();
  const int n = tid >> 6, c = tid & 63;
  const float cnt   = ws[W_CNT + n*CL + c];
  const float inter = ws[W_INT + n*CL + c];
  const float den   = ws[W_DEN + n*CL + c] + cnt;
  const float dice  = 2.f * inter / fmaxf(den, 1e-6f);
  __hip_atomic_fetch_add(&dsum[n], dice, __ATOMIC_RELAXED, __HIP_MEMORY_SCOPE_WORKGROUP);
  __syncthreads();
  if (tid < NIT){
    const float loss = ws[W_VAR + tid] / 64.0f
                     + ws[W_DR + tid]
                     + (1.f - dsum[tid] / 64.0f);
    __hip_atomic_fetch_add(&tot, loss, __ATOMIC_RELAXED, __HIP_MEMORY_SCOPE_WORKGROUP);
  }
  __syncthreads();
  if (tid == 0) out[0] = tot * 0.25f;
}

extern "C" void kernel_launch(void* const* d_in, const int* in_sizes, int n_in,
                              void* d_out, int out_size, void* d_ws, size_t ws_size,
                              hipStream_t stream){
  (void)in_sizes; (void)n_in; (void)out_size; (void)ws_size;
  const float* emb = (const float*)d_in[0];
  const int*   tgt = (const int*)d_in[1];
  float* ws  = (float*)d_ws;
  float* out = (float*)d_out;
  hipMemsetAsync(d_ws, 0, W_TOT*sizeof(float), stream);
  k_sums<<<NIT*256, 256, 0, stream>>>(emb, tgt, ws);
  k_fin <<<NIT,     256, 0, stream>>>(ws);
  k_main<<<NIT*256, 256, 0, stream>>>(emb, tgt, ws);
  k_out <<<1,       256, 0, stream>>>(ws, out);
}